// Round 6
// baseline (61.152 us; speedup 1.0000x reference)
//
#include <hip/hip_runtime.h>

#define TT 4096
#define DD 64
#define NCH3 256
#define CS3 16   // TT / NCH3

// ws layout (in floats)
#define Q_OFF    0
#define K_OFF    (TT*DD)                    // 262144
#define CSUM_OFF (K_OFF + 4*TT*DD)          // 1310720  (8*NCH3*DD = 131072)
#define V_OFF    (CSUM_OFF + 8*NCH3*DD)     // 1441792  (4*TT*2  = 32768)
#define T_OFF    (V_OFF + 8*TT)             // 1474560  (4*TT    = 16384)  ~6 MB

// ---------------------------------------------------------------------------
// Kernel 1: five MLPs + fused 16-row chunk sums + V/t extraction.
// Block = 512 threads (8 waves) per 64-row tile; lane = row; wave w owns
// dims [8w, 8w+8). h in REGISTERS; weights via wave-uniform (scalarizable)
// float4 loads; LDS only at layer boundaries (16B-XOR swizzle, conflict-free).
// Epilogue butterfly (off=1,2,4,8) -> per-16-row sums of K_j[d]*V_j[c].
// ---------------------------------------------------------------------------
__global__ __launch_bounds__(512, 4) void mlp_kernel(
    const float* __restrict__ x1, const float* __restrict__ x2,
    const float* __restrict__ x3, const float* __restrict__ x4,
    const float* __restrict__ Wq_w, const float* __restrict__ Wq_b,
    const float* __restrict__ Wk_w, const float* __restrict__ Wk_b,
    float* __restrict__ ws)
{
    const int q    = blockIdx.x >> 6;    // 0 = Q-mlp, 1..4 = K-mlp (m = q-1)
    const int br   = blockIdx.x & 63;    // row block
    const int lane = threadIdx.x & 63;   // row within tile
    const int w    = threadIdx.x >> 6;   // dim-group 0..7

    const float* x; const float* W; const float* B; float* out;
    if (q == 0) { x = x1; W = Wq_w; B = Wq_b; out = ws + Q_OFF; }
    else {
        const int m = q - 1;
        x = (m == 0) ? x1 : (m == 1) ? x2 : (m == 2) ? x3 : x4;
        W = Wk_w + m * 3 * DD * DD;
        B = Wk_b + m * 3 * DD;
        out = ws + K_OFF + m * TT * DD;
    }

    __shared__ float hs[DD * DD];   // hs[row*64 + ((g ^ (row&7))<<2) + j]
    __shared__ float vb[2 * DD];    // V columns 0,1 of this tile

    // coalesced tile load: 2 float4 per thread; extract V pair + t for free
    {
        const float4* xv = reinterpret_cast<const float4*>(x + br * 64 * DD);
        #pragma unroll
        for (int half = 0; half < 2; ++half) {
            const int idx = threadIdx.x + half * 512;
            const float4 v = xv[idx];
            const int e   = idx * 4;
            const int row = e >> 6;
            const int k0  = e & 63;
            const int slot = ((k0 >> 2) ^ (row & 7)) << 2;
            *reinterpret_cast<float4*>(&hs[row * 64 + slot]) = v;
            if (k0 == 0) {
                vb[row] = v.x; vb[DD + row] = v.y;
                if (q >= 1) {
                    float* vp = ws + V_OFF + ((q - 1) * TT + br * 64 + row) * 2;
                    vp[0] = v.x; vp[1] = v.y;
                }
            }
            if (q >= 1 && k0 == 60) ws[T_OFF + (q - 1) * TT + br * 64 + row] = v.w;
        }
    }

    const int dofs = __builtin_amdgcn_readfirstlane(8 * w);
    const int r3   = lane & 7;

    float h[DD];
    float a[8];

    for (int L = 0; L < 3; ++L) {
        __syncthreads();

        #pragma unroll
        for (int g = 0; g < 16; ++g) {
            const float4 hv = *reinterpret_cast<const float4*>(&hs[lane * 64 + ((g ^ r3) << 2)]);
            h[4*g + 0] = hv.x; h[4*g + 1] = hv.y;
            h[4*g + 2] = hv.z; h[4*g + 3] = hv.w;
        }

        const float* WL = W + L * DD * DD + dofs;   // wave-uniform -> s_load
        const float* BL = B + L * DD + dofs;
        {
            const float4 b0 = *reinterpret_cast<const float4*>(BL);
            const float4 b1 = *reinterpret_cast<const float4*>(BL + 4);
            a[0] = b0.x; a[1] = b0.y; a[2] = b0.z; a[3] = b0.w;
            a[4] = b1.x; a[5] = b1.y; a[6] = b1.z; a[7] = b1.w;
        }

        #pragma unroll
        for (int k = 0; k < DD; ++k) {
            const float hk = h[k];
            const float4 wa = *reinterpret_cast<const float4*>(WL + k * DD);
            const float4 wb = *reinterpret_cast<const float4*>(WL + k * DD + 4);
            a[0] += hk * wa.x; a[1] += hk * wa.y; a[2] += hk * wa.z; a[3] += hk * wa.w;
            a[4] += hk * wb.x; a[5] += hk * wb.y; a[6] += hk * wb.z; a[7] += hk * wb.w;
        }

        if (L < 2) {
            #pragma unroll
            for (int j = 0; j < 8; ++j) a[j] = fmaxf(a[j], 0.f);
            __syncthreads();
            const int g0 = 2 * w;
            *reinterpret_cast<float4*>(&hs[lane * 64 + ((g0 ^ r3) << 2)]) =
                make_float4(a[0], a[1], a[2], a[3]);
            *reinterpret_cast<float4*>(&hs[lane * 64 + (((g0 + 1) ^ r3) << 2)]) =
                make_float4(a[4], a[5], a[6], a[7]);
        }
    }

    // write result rows
    {
        float* o = out + (br * 64 + lane) * DD + dofs;
        *reinterpret_cast<float4*>(o)     = make_float4(a[0], a[1], a[2], a[3]);
        *reinterpret_cast<float4*>(o + 4) = make_float4(a[4], a[5], a[6], a[7]);
    }

    // fused 16-row chunk sums (K-mlps only): csum[mc][ch3][d]
    if (q >= 1) {
        const int m = q - 1;
        const float v0 = vb[lane], v1 = vb[DD + lane];
        float p0[8], p1[8];
        #pragma unroll
        for (int j = 0; j < 8; ++j) { p0[j] = a[j] * v0; p1[j] = a[j] * v1; }
        #pragma unroll
        for (int off = 1; off <= 8; off <<= 1) {
            #pragma unroll
            for (int j = 0; j < 8; ++j) {
                p0[j] += __shfl_xor(p0[j], off);
                p1[j] += __shfl_xor(p1[j], off);
            }
        }
        if ((lane & 15) == 0) {
            const int ch3 = br * 4 + (lane >> 4);
            float* c0 = ws + CSUM_OFF + ((m * 2 + 0) * NCH3 + ch3) * DD + dofs;
            float* c1 = ws + CSUM_OFF + ((m * 2 + 1) * NCH3 + ch3) * DD + dofs;
            #pragma unroll
            for (int j = 0; j < 8; ++j) { c0[j] = p0[j]; c1[j] = p1[j]; }
        }
    }
}

// ---------------------------------------------------------------------------
// Kernel 2: in-place exclusive scan of the 512 (mc,d) chunk chains, 256 long.
// 8 blocks (one per mc) x 64 threads; coalesced, loads pipeline ahead.
// ---------------------------------------------------------------------------
__global__ __launch_bounds__(64) void scan_kernel(float* __restrict__ ws)
{
    const int mc = blockIdx.x;
    const int d  = threadIdx.x;
    float* c = ws + CSUM_OFF + mc * NCH3 * DD + d;
    float run = 0.f;
    #pragma unroll 8
    for (int ch = 0; ch < NCH3; ++ch) {
        const float v = c[ch * DD];
        c[ch * DD] = run;
        run += v;
    }
}

// ---------------------------------------------------------------------------
// Kernel 3: wave-per-row output, NO Z. For each m: binary search p (count of
// t2<=t1), then S = Cpre[p>>4] + in-register partial over <=16 K rows;
// accumulate g[d] over m; single shuffle-dot with Q at the end.
// ---------------------------------------------------------------------------
__global__ __launch_bounds__(256) void out_kernel(
    const float* __restrict__ ws, float* __restrict__ out)
{
    const int lane = threadIdx.x & 63;
    const int wid  = threadIdx.x >> 6;
    const int i = blockIdx.x * 4 + wid;

    const float* Q  = ws + Q_OFF;
    const float* tb = ws + T_OFF;

    const float t1i = tb[0 * TT + i];
    const float qd  = Q[i * DD + lane];

    int lo[4] = {0, 0, 0, 0};
    int hi[4] = {TT, TT, TT, TT};
    #pragma unroll
    for (int s = 0; s < 13; ++s) {
        #pragma unroll
        for (int m = 0; m < 4; ++m) {
            if (lo[m] < hi[m]) {
                const int mid = (lo[m] + hi[m]) >> 1;
                const bool le = tb[m * TT + mid] <= t1i;
                lo[m] = le ? mid + 1 : lo[m];
                hi[m] = le ? hi[m] : mid;
            }
        }
    }

    float g0 = 0.f, g1 = 0.f;     // sum_m S_m,c[lane]
    #pragma unroll
    for (int m = 0; m < 4; ++m) {
        if (lo[m] > 0) {
            const int p    = lo[m] - 1;
            const int ch   = p >> 4;          // CS3=16
            const int base = ch << 4;
            const float* c0 = ws + CSUM_OFF + ((m * 2 + 0) * NCH3 + ch) * DD;
            const float* c1 = ws + CSUM_OFF + ((m * 2 + 1) * NCH3 + ch) * DD;
            g0 += c0[lane];
            g1 += c1[lane];
            const float* K  = ws + K_OFF + m * TT * DD;
            const float* V2 = ws + V_OFF + m * TT * 2;
            for (int j = base; j <= p; ++j) {
                const float kv = K[j * DD + lane];
                g0 += kv * V2[j * 2 + 0];
                g1 += kv * V2[j * 2 + 1];
            }
        }
    }

    float a0 = qd * g0, a1 = qd * g1;
    #pragma unroll
    for (int off = 32; off > 0; off >>= 1) {
        a0 += __shfl_xor(a0, off);
        a1 += __shfl_xor(a1, off);
    }
    if (lane == 0) {
        out[i * 2 + 0] = a0;
        out[i * 2 + 1] = a1;
    }
}

extern "C" void kernel_launch(void* const* d_in, const int* in_sizes, int n_in,
                              void* d_out, int out_size, void* d_ws, size_t ws_size,
                              hipStream_t stream)
{
    const float* x1   = (const float*)d_in[0];
    const float* x2   = (const float*)d_in[1];
    const float* x3   = (const float*)d_in[2];
    const float* x4   = (const float*)d_in[3];
    const float* Wq_w = (const float*)d_in[4];
    const float* Wq_b = (const float*)d_in[5];
    const float* Wk_w = (const float*)d_in[6];
    const float* Wk_b = (const float*)d_in[7];
    float* out = (float*)d_out;
    float* ws  = (float*)d_ws;

    hipLaunchKernelGGL(mlp_kernel,  dim3(5 * 64), dim3(512), 0, stream,
                       x1, x2, x3, x4, Wq_w, Wq_b, Wk_w, Wk_b, ws);
    hipLaunchKernelGGL(scan_kernel, dim3(8), dim3(64), 0, stream, ws);
    hipLaunchKernelGGL(out_kernel,  dim3(TT / 4), dim3(256), 0, stream,
                       ws, out);
}

// Round 7
// 47.226 us; speedup vs baseline: 1.2949x; 1.2949x over previous
//
#include <hip/hip_runtime.h>

#define TT 4096
#define DD 64
#define NCH 64
#define CS 64   // TT / NCH

// ws layout (in floats)
#define Q_OFF    0
#define K_OFF    (TT*DD)                  // 262144
#define Z_OFF    (K_OFF + 4*TT*DD)        // 1310720
#define CSUM_OFF (Z_OFF + 8*TT*DD)        // 3407872  (8*NCH*DD = 32768)
#define T_OFF    (CSUM_OFF + 8*NCH*DD)    // 3440640  (4*TT = 16384)  ~13.8 MB total

// ---------------------------------------------------------------------------
// Kernel 1: five MLPs (r3 structure, verbatim inner loop) + fused chunk sums.
// Block = 1024 threads (16 waves) over a 64-row tile; wave w owns output dims
// [4w, 4w+4). Coalesced tile load into transposed padded LDS h[k*65+row]
// (2-way bank aliasing = free). Wave-uniform (readfirstlane'd) weight float4
// loads, k-loop unroll 8. t-values extracted free during the tile load.
// NEW vs r3: chunksum fused as an epilogue — V columns cached in vb[] during
// the tile load; full 64-lane butterfly reduces K[row][d]*V[row][c] over the
// tile's 64 rows -> csum[mc][br][d] (raw, zfill folds the prefix as before).
// ---------------------------------------------------------------------------
__global__ __launch_bounds__(1024) void mlp_kernel(
    const float* __restrict__ x1, const float* __restrict__ x2,
    const float* __restrict__ x3, const float* __restrict__ x4,
    const float* __restrict__ Wq_w, const float* __restrict__ Wq_b,
    const float* __restrict__ Wk_w, const float* __restrict__ Wk_b,
    float* __restrict__ ws)
{
    const int q    = blockIdx.x >> 6;    // 0 = Q-mlp, 1..4 = K-mlp (m = q-1)
    const int br   = blockIdx.x & 63;    // row block (= chunk)
    const int lane = threadIdx.x & 63;
    const int w    = threadIdx.x >> 6;   // 0..15

    const float* x; const float* W; const float* B; float* out;
    if (q == 0) { x = x1; W = Wq_w; B = Wq_b; out = ws + Q_OFF; }
    else {
        const int m = q - 1;
        x = (m == 0) ? x1 : (m == 1) ? x2 : (m == 2) ? x3 : x4;
        W = Wk_w + m * 3 * DD * DD;
        B = Wk_b + m * 3 * DD;
        out = ws + K_OFF + m * TT * DD;
    }

    __shared__ float h[DD * 65];   // h[k*65 + row], padded
    __shared__ float vb[2 * DD];   // V columns 0,1 of this tile

    // coalesced tile load: 64 rows x 64 dims = 4096 floats = 1024 float4
    {
        const float4 v = reinterpret_cast<const float4*>(x + br * 64 * DD)[threadIdx.x];
        const int e   = threadIdx.x * 4;
        const int row = e >> 6;
        const int k0  = e & 63;
        h[(k0 + 0) * 65 + row] = v.x;
        h[(k0 + 1) * 65 + row] = v.y;
        h[(k0 + 2) * 65 + row] = v.z;
        h[(k0 + 3) * 65 + row] = v.w;
        if (k0 == 0) { vb[row] = v.x; vb[DD + row] = v.y; }
        if (q >= 1 && k0 == 60) {               // free t-extraction (x[:,63])
            ws[T_OFF + (q - 1) * TT + br * 64 + row] = v.w;
        }
    }

    const int dofs = __builtin_amdgcn_readfirstlane(4 * w);

    float a0, a1, a2, a3;
    for (int L = 0; L < 3; ++L) {
        __syncthreads();
        const float* WL = W + L * DD * DD + dofs;
        const float* BL = B + L * DD + dofs;
        a0 = BL[0]; a1 = BL[1]; a2 = BL[2]; a3 = BL[3];

        #pragma unroll 8
        for (int k = 0; k < DD; ++k) {
            const float hk = h[k * 65 + lane];
            const float4 wv = *reinterpret_cast<const float4*>(WL + k * DD);
            a0 += hk * wv.x; a1 += hk * wv.y; a2 += hk * wv.z; a3 += hk * wv.w;
        }

        if (L < 2) {
            a0 = fmaxf(a0, 0.f); a1 = fmaxf(a1, 0.f);
            a2 = fmaxf(a2, 0.f); a3 = fmaxf(a3, 0.f);
            __syncthreads();
            h[(dofs + 0) * 65 + lane] = a0;
            h[(dofs + 1) * 65 + lane] = a1;
            h[(dofs + 2) * 65 + lane] = a2;
            h[(dofs + 3) * 65 + lane] = a3;
        }
    }

    // write result rows
    {
        float* o = out + (br * 64 + lane) * DD + dofs;
        *reinterpret_cast<float4*>(o) = make_float4(a0, a1, a2, a3);
    }

    // fused chunk sums (K-mlps only): csum[mc][br][d] = sum_rows K[row][d]*V[row][c]
    if (q >= 1) {
        const int m = q - 1;
        const float v0 = vb[lane], v1 = vb[DD + lane];
        float p00 = a0 * v0, p01 = a1 * v0, p02 = a2 * v0, p03 = a3 * v0;
        float p10 = a0 * v1, p11 = a1 * v1, p12 = a2 * v1, p13 = a3 * v1;
        #pragma unroll
        for (int off = 1; off <= 32; off <<= 1) {
            p00 += __shfl_xor(p00, off); p01 += __shfl_xor(p01, off);
            p02 += __shfl_xor(p02, off); p03 += __shfl_xor(p03, off);
            p10 += __shfl_xor(p10, off); p11 += __shfl_xor(p11, off);
            p12 += __shfl_xor(p12, off); p13 += __shfl_xor(p13, off);
        }
        if (lane == 0) {
            float* c0 = ws + CSUM_OFF + ((m * 2 + 0) * NCH + br) * DD + dofs;
            float* c1 = ws + CSUM_OFF + ((m * 2 + 1) * NCH + br) * DD + dofs;
            c0[0] = p00; c0[1] = p01; c0[2] = p02; c0[3] = p03;
            c1[0] = p10; c1[1] = p11; c1[2] = p12; c1[3] = p13;
        }
    }
}

// ---------------------------------------------------------------------------
// Kernel 2: inclusive prefix Z[mc][j][d]. One wave per (mc, ch). Chunk-prefix
// fold uses UNCONDITIONAL loads + select so all 63 loads pipeline in one
// latency burst; main loop unrolled so K loads prefetch ahead of the FMA chain.
// (verbatim r3)
// ---------------------------------------------------------------------------
__global__ __launch_bounds__(64) void zfill_kernel(
    const float* __restrict__ x1, const float* __restrict__ x2,
    const float* __restrict__ x3, const float* __restrict__ x4,
    float* __restrict__ ws)
{
    const int mc = blockIdx.x >> 6;    // m*2 + c
    const int ch = blockIdx.x & 63;
    const int m  = mc >> 1;
    const int c  = mc & 1;
    const int d  = threadIdx.x;
    const float* xm = (m == 0) ? x1 : (m == 1) ? x2 : (m == 2) ? x3 : x4;
    const float* K = ws + K_OFF + m * TT * DD;
    const float* csum = ws + CSUM_OFF + mc * NCH * DD;
    float* Z = ws + Z_OFF + mc * TT * DD;

    float r = 0.f;
    #pragma unroll
    for (int cc = 0; cc < NCH - 1; ++cc) {
        const float v = csum[cc * DD + d];
        r += (cc < ch) ? v : 0.f;
    }

    const int j0 = ch * CS;
    #pragma unroll 8
    for (int jj = 0; jj < CS; ++jj) {
        const int j = j0 + jj;
        r += K[j * DD + d] * xm[j * DD + c];
        Z[j * DD + d] = r;
    }
}

// ---------------------------------------------------------------------------
// Kernel 3: wave-per-row output. 4 binary searches interleaved (independent
// chains) on dense t-arrays, then out_i = Q_i . Z[p-1], 64-lane shuffle reduce.
// (verbatim r3)
// ---------------------------------------------------------------------------
__global__ __launch_bounds__(256) void gather_kernel(
    const float* __restrict__ ws, float* __restrict__ out)
{
    const int lane = threadIdx.x & 63;
    const int wid  = threadIdx.x >> 6;
    const int i = blockIdx.x * 4 + wid;

    const float* Q  = ws + Q_OFF;
    const float* Z  = ws + Z_OFF;
    const float* tb = ws + T_OFF;

    const float t1i = tb[0 * TT + i];
    const float qd  = Q[i * DD + lane];

    int lo[4] = {0, 0, 0, 0};
    int hi[4] = {TT, TT, TT, TT};
    #pragma unroll
    for (int s = 0; s < 13; ++s) {
        #pragma unroll
        for (int m = 0; m < 4; ++m) {
            if (lo[m] < hi[m]) {
                const int mid = (lo[m] + hi[m]) >> 1;
                const bool le = tb[m * TT + mid] <= t1i;
                lo[m] = le ? mid + 1 : lo[m];
                hi[m] = le ? hi[m] : mid;
            }
        }
    }

    float a0 = 0.f, a1 = 0.f;
    #pragma unroll
    for (int m = 0; m < 4; ++m) {
        if (lo[m] > 0) {
            const int p = lo[m] - 1;
            a0 += qd * Z[((m * 2 + 0) * TT + p) * DD + lane];
            a1 += qd * Z[((m * 2 + 1) * TT + p) * DD + lane];
        }
    }

    #pragma unroll
    for (int off = 32; off > 0; off >>= 1) {
        a0 += __shfl_xor(a0, off);
        a1 += __shfl_xor(a1, off);
    }
    if (lane == 0) {
        out[i * 2 + 0] = a0;
        out[i * 2 + 1] = a1;
    }
}

extern "C" void kernel_launch(void* const* d_in, const int* in_sizes, int n_in,
                              void* d_out, int out_size, void* d_ws, size_t ws_size,
                              hipStream_t stream)
{
    const float* x1   = (const float*)d_in[0];
    const float* x2   = (const float*)d_in[1];
    const float* x3   = (const float*)d_in[2];
    const float* x4   = (const float*)d_in[3];
    const float* Wq_w = (const float*)d_in[4];
    const float* Wq_b = (const float*)d_in[5];
    const float* Wk_w = (const float*)d_in[6];
    const float* Wk_b = (const float*)d_in[7];
    float* out = (float*)d_out;
    float* ws  = (float*)d_ws;

    hipLaunchKernelGGL(mlp_kernel,   dim3(5 * 64), dim3(1024), 0, stream,
                       x1, x2, x3, x4, Wq_w, Wq_b, Wk_w, Wk_b, ws);
    hipLaunchKernelGGL(zfill_kernel, dim3(8 * NCH), dim3(64), 0, stream,
                       x1, x2, x3, x4, ws);
    hipLaunchKernelGGL(gather_kernel, dim3(TT / 4), dim3(256), 0, stream,
                       ws, out);
}

// Round 8
// 42.139 us; speedup vs baseline: 1.4512x; 1.1207x over previous
//
#include <hip/hip_runtime.h>

typedef __attribute__((ext_vector_type(8))) short bf16x8;
typedef __attribute__((ext_vector_type(4))) float f32x4;
typedef __attribute__((ext_vector_type(4))) unsigned int u32x4;

#define TT 4096
#define DD 64
#define NCH2 128
#define CS2 32   // TT / NCH2

// ws layout (in floats)
#define Q_OFF    0
#define K_OFF    (TT*DD)                    // 262144
#define Z_OFF    (K_OFF + 4*TT*DD)          // 1310720
#define CSUM_OFF (Z_OFF + 8*TT*DD)          // 3407872  (8*NCH2*DD = 65536)
#define T_OFF    (CSUM_OFF + 8*NCH2*DD)     // 3473408  (4*TT = 16384)
#define WP_OFF   (T_OFF + 4*TT)             // 3489792  (+61440 floats) ~14.2 MB
#define WP_HALF  61440   // ushorts per precision half (15*2*4*64*8)

// ---------------------------------------------------------------------------
// Kernel 0: pack all 15 layer matrices into MFMA B-fragment layout, bf16
// hi/lo split (hi = truncate, lo = RNE(w - hi)).  Fragment (t,n): lane l
// supplies W[k = t*32+(l>>4)*8+j][c = n*16+(l&15)], j=0..7 contiguous ->
// per-lane 16B, lanes consecutive -> coalesced dwordx4 frag loads in mlpmm.
// ---------------------------------------------------------------------------
__global__ __launch_bounds__(256) void wpack_kernel(
    const float* __restrict__ Wq_w, const float* __restrict__ Wk_w,
    float* __restrict__ ws)
{
    const int ell = blockIdx.x;           // 0..14 = q*3 + L
    const int q = ell / 3, L = ell % 3;
    const float* Wsrc = (q == 0) ? (Wq_w + L * DD * DD)
                                 : (Wk_w + ((q - 1) * 3 + L) * DD * DD);
    unsigned short* wp = reinterpret_cast<unsigned short*>(ws + WP_OFF);
    for (int idx = threadIdx.x; idx < 4096; idx += 256) {
        const int j = idx & 7;
        const int l = (idx >> 3) & 63;
        const int n = (idx >> 9) & 3;
        const int t = (idx >> 11) & 1;
        const int k = t * 32 + (l >> 4) * 8 + j;
        const int c = n * 16 + (l & 15);
        const float wv = Wsrc[k * DD + c];
        const unsigned int u = __float_as_uint(wv);
        const unsigned short hi = (unsigned short)(u >> 16);
        const float hif = __uint_as_float(((unsigned int)hi) << 16);
        const float lof = wv - hif;
        const unsigned int v = __float_as_uint(lof);
        const unsigned short lo = (unsigned short)((v + 0x7FFFu + ((v >> 16) & 1u)) >> 16);
        const int dst = (((ell * 2 + t) * 4 + n) * 64 + l) * 8 + j;
        wp[dst] = hi;
        wp[WP_HALF + dst] = lo;
    }
}

// ---------------------------------------------------------------------------
// Kernel 1: five MLPs via MFMA (split-bf16, 3 terms: hh + hl + lh) + fused
// 32-row chunk sums + V/t extraction.
// Block = 128 threads (2 waves) per 32-row tile; wave w owns rows [16w,16w+16)
// as ONE 16x16x32-mfma M-tile (full 64 output cols = 4 N-tiles, 2 K-tiles).
// W lives in registers as fragments (64 VGPRs hi+lo) -> no per-k weight
// streaming.  h tile in LDS, row stride 68 (16B-aligned b128 reads, bank-
// spread epilogue writes).  No barrier between layers (wave-private rows).
// ---------------------------------------------------------------------------
__global__ __launch_bounds__(128) void mlpmm_kernel(
    const float* __restrict__ x1, const float* __restrict__ x2,
    const float* __restrict__ x3, const float* __restrict__ x4,
    const float* __restrict__ Wq_b, const float* __restrict__ Wk_b,
    float* __restrict__ ws)
{
    const int q   = blockIdx.x >> 7;    // 0 = Q-mlp, 1..4 = K-mlp (m = q-1)
    const int rb  = blockIdx.x & 127;   // 32-row block (= chunk, NCH2=128)
    const int tid = threadIdx.x;
    const int l   = tid & 63;
    const int w   = tid >> 6;           // wave 0..1

    const float* x; const float* Bsrc; float* out;
    if (q == 0) { x = x1; Bsrc = Wq_b; out = ws + Q_OFF; }
    else {
        const int m = q - 1;
        x = (m == 0) ? x1 : (m == 1) ? x2 : (m == 2) ? x3 : x4;
        Bsrc = Wk_b + m * 3 * DD;
        out = ws + K_OFF + m * TT * DD;
    }

    __shared__ float hs[32 * 68];
    __shared__ float vb[2 * 32];
    __shared__ float ps[2][2][64];

    // coalesced tile load: 32 rows x 64 dims = 512 float4
    {
        const float4* xv = reinterpret_cast<const float4*>(x + rb * 32 * DD);
        #pragma unroll
        for (int i = 0; i < 4; ++i) {
            const int idx = tid + i * 128;
            const float4 v = xv[idx];
            const int e = idx * 4;
            const int row = e >> 6, k0 = e & 63;
            *reinterpret_cast<float4*>(&hs[row * 68 + k0]) = v;
            if (k0 == 0) { vb[row] = v.x; vb[32 + row] = v.y; }
            if (q >= 1 && k0 == 60) ws[T_OFF + (q - 1) * TT + rb * 32 + row] = v.w;
        }
    }
    __syncthreads();

    const unsigned short* wp = reinterpret_cast<const unsigned short*>(ws + WP_OFF);
    const int lane15 = l & 15, lhi = l >> 4;
    const int wrow = w * 16;

    for (int L = 0; L < 3; ++L) {
        // B fragments (hi+lo) for this layer: 16 coalesced 16B loads
        bf16x8 bh[2][4], bl[2][4];
        #pragma unroll
        for (int t = 0; t < 2; ++t) {
            #pragma unroll
            for (int n = 0; n < 4; ++n) {
                const int f = ((((q * 3 + L) * 2 + t) * 4 + n) * 64 + l) * 8;
                bh[t][n] = *reinterpret_cast<const bf16x8*>(wp + f);
                bl[t][n] = *reinterpret_cast<const bf16x8*>(wp + WP_HALF + f);
            }
        }

        // A fragments from LDS + split-bf16 conversion
        bf16x8 ah[2], al[2];
        #pragma unroll
        for (int t = 0; t < 2; ++t) {
            const float* src = &hs[(wrow + lane15) * 68 + t * 32 + lhi * 8];
            float x8[8];
            *reinterpret_cast<float4*>(&x8[0]) = *reinterpret_cast<const float4*>(src);
            *reinterpret_cast<float4*>(&x8[4]) = *reinterpret_cast<const float4*>(src + 4);
            unsigned int hw[4], lw[4];
            #pragma unroll
            for (int p = 0; p < 4; ++p) {
                const unsigned int u0 = __float_as_uint(x8[2*p]);
                const unsigned int u1 = __float_as_uint(x8[2*p+1]);
                const unsigned int h0 = u0 >> 16, h1 = u1 >> 16;
                const float f0 = x8[2*p]   - __uint_as_float(h0 << 16);
                const float f1 = x8[2*p+1] - __uint_as_float(h1 << 16);
                const unsigned int v0 = __float_as_uint(f0), v1 = __float_as_uint(f1);
                const unsigned int l0 = (v0 + 0x7FFFu + ((v0 >> 16) & 1u)) >> 16;
                const unsigned int l1 = (v1 + 0x7FFFu + ((v1 >> 16) & 1u)) >> 16;
                hw[p] = h0 | (h1 << 16);
                lw[p] = l0 | (l1 << 16);
            }
            const u32x4 hv = {hw[0], hw[1], hw[2], hw[3]};
            const u32x4 lv = {lw[0], lw[1], lw[2], lw[3]};
            ah[t] = __builtin_bit_cast(bf16x8, hv);
            al[t] = __builtin_bit_cast(bf16x8, lv);
        }

        f32x4 acc[4];
        #pragma unroll
        for (int n = 0; n < 4; ++n) acc[n] = (f32x4){0.f, 0.f, 0.f, 0.f};

        #pragma unroll
        for (int t = 0; t < 2; ++t) {
            #pragma unroll
            for (int n = 0; n < 4; ++n) {
                acc[n] = __builtin_amdgcn_mfma_f32_16x16x32_bf16(ah[t], bh[t][n], acc[n], 0, 0, 0);
                acc[n] = __builtin_amdgcn_mfma_f32_16x16x32_bf16(ah[t], bl[t][n], acc[n], 0, 0, 0);
                acc[n] = __builtin_amdgcn_mfma_f32_16x16x32_bf16(al[t], bh[t][n], acc[n], 0, 0, 0);
            }
        }

        // epilogue: bias (+ReLU), back to LDS (own rows only -> no barrier)
        #pragma unroll
        for (int n = 0; n < 4; ++n) {
            const float bv = Bsrc[L * DD + n * 16 + lane15];
            #pragma unroll
            for (int r = 0; r < 4; ++r) {
                float val = acc[n][r] + bv;
                if (L < 2) val = fmaxf(val, 0.f);
                hs[(wrow + lhi * 4 + r) * 68 + n * 16 + lane15] = val;
            }
        }
    }

    // write result rows (coalesced)
    #pragma unroll
    for (int rr = 0; rr < 16; ++rr) {
        out[(rb * 32 + wrow + rr) * DD + l] = hs[(wrow + rr) * 68 + l];
    }

    // fused 32-row chunk sums (K-mlps only): csum[mc][rb][d]
    if (q >= 1) {
        __syncthreads();
        const int m = q - 1;
        const int d = tid & 63;
        const int g = tid >> 6;     // 0..1
        float p0 = 0.f, p1 = 0.f;
        #pragma unroll
        for (int rr = 0; rr < 16; ++rr) {
            const int row = g * 16 + rr;
            const float kv = hs[row * 68 + d];
            p0 += kv * vb[row];
            p1 += kv * vb[32 + row];
        }
        ps[g][0][d] = p0; ps[g][1][d] = p1;
        __syncthreads();
        const int c = g;
        const float s = ps[0][c][d] + ps[1][c][d];
        ws[CSUM_OFF + ((m * 2 + c) * NCH2 + rb) * DD + d] = s;
    }
}

// ---------------------------------------------------------------------------
// Kernel 2: inclusive prefix Z[mc][j][d]. One wave per (mc, ch2), CS2=32.
// Chunk-prefix fold = one burst of 127 unconditional coalesced loads + select.
// (verbatim r3)
// ---------------------------------------------------------------------------
__global__ __launch_bounds__(64) void zfill_kernel(
    const float* __restrict__ x1, const float* __restrict__ x2,
    const float* __restrict__ x3, const float* __restrict__ x4,
    float* __restrict__ ws)
{
    const int mc  = blockIdx.x >> 7;   // m*2 + c
    const int ch2 = blockIdx.x & 127;
    const int m   = mc >> 1;
    const int c   = mc & 1;
    const int d   = threadIdx.x;
    const float* xm = (m == 0) ? x1 : (m == 1) ? x2 : (m == 2) ? x3 : x4;
    const float* K = ws + K_OFF + m * TT * DD;
    const float* csum = ws + CSUM_OFF + mc * NCH2 * DD;
    float* Z = ws + Z_OFF + mc * TT * DD;

    float r = 0.f;
    #pragma unroll
    for (int cc = 0; cc < NCH2 - 1; ++cc) {
        const float v = csum[cc * DD + d];
        r += (cc < ch2) ? v : 0.f;
    }

    const int j0 = ch2 * CS2;
    #pragma unroll 8
    for (int jj = 0; jj < CS2; ++jj) {
        const int j = j0 + jj;
        r += K[j * DD + d] * xm[j * DD + c];
        Z[j * DD + d] = r;
    }
}

// ---------------------------------------------------------------------------
// Kernel 3: wave-per-row output. 4 binary searches interleaved (independent
// chains) on dense t-arrays, then out_i = Q_i . Z[p-1], 64-lane shuffle reduce.
// (verbatim r3)
// ---------------------------------------------------------------------------
__global__ __launch_bounds__(256) void gather_kernel(
    const float* __restrict__ ws, float* __restrict__ out)
{
    const int lane = threadIdx.x & 63;
    const int wid  = threadIdx.x >> 6;
    const int i = blockIdx.x * 4 + wid;

    const float* Q  = ws + Q_OFF;
    const float* Z  = ws + Z_OFF;
    const float* tb = ws + T_OFF;

    const float t1i = tb[0 * TT + i];
    const float qd  = Q[i * DD + lane];

    int lo[4] = {0, 0, 0, 0};
    int hi[4] = {TT, TT, TT, TT};
    #pragma unroll
    for (int s = 0; s < 13; ++s) {
        #pragma unroll
        for (int m = 0; m < 4; ++m) {
            if (lo[m] < hi[m]) {
                const int mid = (lo[m] + hi[m]) >> 1;
                const bool le = tb[m * TT + mid] <= t1i;
                lo[m] = le ? mid + 1 : lo[m];
                hi[m] = le ? hi[m] : mid;
            }
        }
    }

    float a0 = 0.f, a1 = 0.f;
    #pragma unroll
    for (int m = 0; m < 4; ++m) {
        if (lo[m] > 0) {
            const int p = lo[m] - 1;
            a0 += qd * Z[((m * 2 + 0) * TT + p) * DD + lane];
            a1 += qd * Z[((m * 2 + 1) * TT + p) * DD + lane];
        }
    }

    #pragma unroll
    for (int off = 32; off > 0; off >>= 1) {
        a0 += __shfl_xor(a0, off);
        a1 += __shfl_xor(a1, off);
    }
    if (lane == 0) {
        out[i * 2 + 0] = a0;
        out[i * 2 + 1] = a1;
    }
}

extern "C" void kernel_launch(void* const* d_in, const int* in_sizes, int n_in,
                              void* d_out, int out_size, void* d_ws, size_t ws_size,
                              hipStream_t stream)
{
    const float* x1   = (const float*)d_in[0];
    const float* x2   = (const float*)d_in[1];
    const float* x3   = (const float*)d_in[2];
    const float* x4   = (const float*)d_in[3];
    const float* Wq_w = (const float*)d_in[4];
    const float* Wq_b = (const float*)d_in[5];
    const float* Wk_w = (const float*)d_in[6];
    const float* Wk_b = (const float*)d_in[7];
    float* out = (float*)d_out;
    float* ws  = (float*)d_ws;

    hipLaunchKernelGGL(wpack_kernel, dim3(15), dim3(256), 0, stream,
                       Wq_w, Wk_w, ws);
    hipLaunchKernelGGL(mlpmm_kernel, dim3(5 * 128), dim3(128), 0, stream,
                       x1, x2, x3, x4, Wq_b, Wk_b, ws);
    hipLaunchKernelGGL(zfill_kernel, dim3(8 * NCH2), dim3(64), 0, stream,
                       x1, x2, x3, x4, ws);
    hipLaunchKernelGGL(gather_kernel, dim3(TT / 4), dim3(256), 0, stream,
                       ws, out);
}